// Round 4
// baseline (466.963 us; speedup 1.0000x reference)
//
#include <hip/hip_runtime.h>
#include <hip/hip_bf16.h>

#define NTOT 8192
#define DDIM 256
#define ROWS 32                 // rows per attn block
#define JSPL 2                  // j-split: 512 blocks total
#define JHALF (NTOT / JSPL)     // 4096 j per block
#define NBATCH 64               // batches per block; batch = 2 tiles x 32 j = 64 j
#define NTSTR 131584            // hTf nt-stride in elems: 257*64*8
#define HTF_ELEMS (16 * NTSTR)
#define PSTR 40                 // P LDS row stride in ushorts (80 B, 16B-aligned, bank-spread)

typedef __attribute__((ext_vector_type(8))) short short8;
typedef __attribute__((ext_vector_type(4))) short short4v;
typedef __attribute__((ext_vector_type(4))) float floatx4;
typedef __attribute__((ext_vector_type(4))) int intx4;

static __device__ __forceinline__ short bfp(float f) {
  __hip_bfloat16 b = __float2bfloat16(f);
  return *(short*)&b;
}

// ------- per-row exp tables: rc=(e^s1, e^.01s1), etab=(e^s2, e^.01s2)
// leaky-exp select is a max: exp(leaky(s1+s2)) = max(e^s1*e^s2, e^.01s1*e^.01s2)
__global__ __launch_bounds__(256) void gat_scores(const float* __restrict__ h,
                                                  const float* __restrict__ a,
                                                  float4* __restrict__ rc,
                                                  float2* __restrict__ etab) {
  int row  = blockIdx.x * 4 + (threadIdx.x >> 6);
  int lane = threadIdx.x & 63;
  const float* hr = h + (size_t)row * DDIM;
  float p1 = 0.f, p2 = 0.f;
#pragma unroll
  for (int k = 0; k < DDIM / 64; ++k) {
    int idx  = lane + 64 * k;
    float hv = hr[idx];
    p1 += hv * a[idx];
    p2 += hv * a[DDIM + idx];
  }
#pragma unroll
  for (int off = 32; off > 0; off >>= 1) {
    p1 += __shfl_down(p1, off, 64);
    p2 += __shfl_down(p2, off, 64);
  }
  if (lane == 0) {
    rc[row]   = make_float4(__expf(p1), __expf(0.01f * p1), 0.f, 0.f);
    etab[row] = make_float2(__expf(p2), __expf(0.01f * p2));
  }
}

// ---------------- pack h -> fragment-major bf16 hTf (padded nt-stride) ------
// hTf[((n*257 + jblk)*64 + lane)*8 + i] = H[jblk*32 + (lane>>4)*8 + i][n*16 + (lane&15)]
__global__ __launch_bounds__(256) void gat_hpack(const float* __restrict__ h,
                                                 ushort* __restrict__ hTf) {
  __shared__ float tile[64][257];
  const int t    = threadIdx.x;
  const int lane = t & 63;
  const int w    = t >> 6;
  const int quad = lane >> 4;
  const int c    = lane & 15;
  const int i0   = blockIdx.x * 64;

#pragma unroll
  for (int it = 0; it < 16; ++it) {
    int r = it * 4 + w;
    float4 v = *(const float4*)(h + (size_t)(i0 + r) * DDIM + lane * 4);
    tile[r][lane * 4 + 0] = v.x; tile[r][lane * 4 + 1] = v.y;
    tile[r][lane * 4 + 2] = v.z; tile[r][lane * 4 + 3] = v.w;
  }
  __syncthreads();

#pragma unroll
  for (int k = 0; k < 4; ++k) {
    const int n = 4 * k + w;
#pragma unroll
    for (int jbl = 0; jbl < 2; ++jbl) {
      short8 vv;
#pragma unroll
      for (int i = 0; i < 8; ++i) {
        float f = tile[jbl * 32 + quad * 8 + i][n * 16 + c];
        vv[i] = bfp(f);
      }
      *(short8*)(hTf + ((size_t)(n * 257 + i0 / 32 + jbl) * 64 + lane) * 8) = vv;
    }
  }
}

// ---------------- col-split fused softmax-num + P@h partials via MFMA -------
// grid (256, 2) x 512 thr (8 waves). Block (bx, jb): rows [32bx,+32), j in
// [4096jb,+4096). P built cooperatively ONCE per block into LDS (bf16,
// stride-80 rows), double-buffered, 1 barrier/batch. Wave w owns output cols
// [32w,+32) -> acc is only 16 regs/thread; total regs ~110 -> 4 waves/SIMD,
// 2 blocks/CU. All reg-slot indices are macro literals (no scratch).
__global__ __launch_bounds__(512, 4) void gat_attn(const ushort* __restrict__ hTf,
                                                   const int* __restrict__ adj,
                                                   const float4* __restrict__ rc,
                                                   const float2* __restrict__ etab,
                                                   float* __restrict__ pout,
                                                   float* __restrict__ plp) {
  __shared__ __align__(16) ushort Pb[2][2][32 * PSTR];  // [buf][tile][row*PSTR+k] = 10 KB
  __shared__ float lsum[8][32];

  const int t    = threadIdx.x;
  const int lane = t & 63;
  const int w    = t >> 6;
  const int quad = lane >> 4;
  const int c    = lane & 15;
  const int r0   = blockIdx.x * ROWS;
  const int jb   = blockIdx.y;

  // ---- P-build role: lane builds row brow, tile btile, k-offsets bjo..bjo+4
  const int brow  = lane & 31;
  const int btile = w & 1;
  const int bjo   = ((w >> 1) * 2 + (lane >> 5)) * 4;
  const float4 rcv = rc[r0 + brow];
  const float E1 = rcv.x, E2 = rcv.y;

  const int*   abase = adj + (size_t)(r0 + brow) * NTOT + (size_t)jb * JHALF + btile * 32 + bjo;
  const float* ebase = (const float*)(etab + (size_t)jb * JHALF + btile * 32 + bjo);
  // ---- MFMA role: wave owns col frags n = 2w, 2w+1
  const ushort* hbase = hTf + (size_t)(2 * w) * NTSTR + ((size_t)(jb * 128) * 64 + lane) * 8;

  floatx4 acc[2][2];
#pragma unroll
  for (int rt = 0; rt < 2; ++rt)
#pragma unroll
    for (int nn = 0; nn < 2; ++nn) acc[rt][nn] = (floatx4){0.f, 0.f, 0.f, 0.f};

  float lps = 0.f, lpdead = 0.f;
  intx4  ajs[2];
  float4 es[2][2];
  short8 bD[2][4];

  #define LDAE(S, bp)                                                          \
    ajs[S]   = __builtin_nontemporal_load((const intx4*)(abase + (bp) * 64));  \
    es[S][0] = *(const float4*)(ebase + (bp) * 128);                           \
    es[S][1] = *(const float4*)(ebase + (bp) * 128 + 4);

  #define LDB(S, bp)                                                           \
    bD[S][0] = *(const short8*)(hbase + (size_t)((bp) * 2 + 0) * 512);         \
    bD[S][1] = *(const short8*)(hbase + NTSTR + (size_t)((bp) * 2 + 0) * 512); \
    bD[S][2] = *(const short8*)(hbase + (size_t)((bp) * 2 + 1) * 512);         \
    bD[S][3] = *(const short8*)(hbase + NTSTR + (size_t)((bp) * 2 + 1) * 512);

  #define BUILD(S, LACC)                                                       \
    {                                                                          \
      short4v pk; float p;                                                     \
      p = (ajs[S][0] > 0) ? fmaxf(E1 * es[S][0].x, E2 * es[S][0].y) : 0.f; LACC += p; pk[0] = bfp(p); \
      p = (ajs[S][1] > 0) ? fmaxf(E1 * es[S][0].z, E2 * es[S][0].w) : 0.f; LACC += p; pk[1] = bfp(p); \
      p = (ajs[S][2] > 0) ? fmaxf(E1 * es[S][1].x, E2 * es[S][1].y) : 0.f; LACC += p; pk[2] = bfp(p); \
      p = (ajs[S][3] > 0) ? fmaxf(E1 * es[S][1].z, E2 * es[S][1].w) : 0.f; LACC += p; pk[3] = bfp(p); \
      *(short4v*)&Pb[S][btile][brow * PSTR + bjo] = pk;                        \
    }

  // ---- prologue: batches 0,1 staged; batch 0 built into Pb[0] (no lps) ----
  LDAE(0, 0)
  LDAE(1, 1)
  LDB(0, 0)
  LDB(1, 1)
  BUILD(0, lpdead)
  __syncthreads();

  // ITER(bt, CUR, NXT): MFMA batch bt from Pb[CUR]/bD[CUR]; build bt+1 from
  // slot NXT regs into Pb[NXT]; prefetch bt+2 into slot CUR; barrier.
  #define ITER(bt, CUR, NXT)                                                   \
    {                                                                          \
      short8 pa00 = *(const short8*)&Pb[CUR][0][c * PSTR + quad * 8];          \
      short8 pa01 = *(const short8*)&Pb[CUR][0][(16 + c) * PSTR + quad * 8];   \
      short8 pa10 = *(const short8*)&Pb[CUR][1][c * PSTR + quad * 8];          \
      short8 pa11 = *(const short8*)&Pb[CUR][1][(16 + c) * PSTR + quad * 8];   \
      BUILD(NXT, lps)                                                          \
      {                                                                        \
        const int bp = ((bt) + 2) & (NBATCH - 1);                              \
        LDAE(CUR, bp)                                                          \
      }                                                                        \
      acc[0][0] = __builtin_amdgcn_mfma_f32_16x16x32_bf16(pa00, bD[CUR][0], acc[0][0], 0, 0, 0); \
      acc[0][1] = __builtin_amdgcn_mfma_f32_16x16x32_bf16(pa00, bD[CUR][1], acc[0][1], 0, 0, 0); \
      acc[1][0] = __builtin_amdgcn_mfma_f32_16x16x32_bf16(pa01, bD[CUR][0], acc[1][0], 0, 0, 0); \
      acc[1][1] = __builtin_amdgcn_mfma_f32_16x16x32_bf16(pa01, bD[CUR][1], acc[1][1], 0, 0, 0); \
      acc[0][0] = __builtin_amdgcn_mfma_f32_16x16x32_bf16(pa10, bD[CUR][2], acc[0][0], 0, 0, 0); \
      acc[0][1] = __builtin_amdgcn_mfma_f32_16x16x32_bf16(pa10, bD[CUR][3], acc[0][1], 0, 0, 0); \
      acc[1][0] = __builtin_amdgcn_mfma_f32_16x16x32_bf16(pa11, bD[CUR][2], acc[1][0], 0, 0, 0); \
      acc[1][1] = __builtin_amdgcn_mfma_f32_16x16x32_bf16(pa11, bD[CUR][3], acc[1][1], 0, 0, 0); \
      {                                                                        \
        const int bp = ((bt) + 2) & (NBATCH - 1);                              \
        LDB(CUR, bp)                                                           \
      }                                                                        \
      __syncthreads();                                                         \
    }

  for (int tt = 0; tt < NBATCH; tt += 2) {
    ITER(tt, 0, 1)
    ITER(tt + 1, 1, 0)
  }
  #undef ITER
  #undef BUILD
  #undef LDB
  #undef LDAE

  // ---- softmax denominator: per-row partial over this block's j-half ----
  lps += __shfl_xor(lps, 32, 64);
  if (lane < 32) lsum[w][lane] = lps;
  __syncthreads();
  if (w == 0 && lane < 32) {
    float s = 0.f;
#pragma unroll
    for (int wi = 0; wi < 8; ++wi) s += lsum[wi][lane];
    plp[(size_t)jb * NTOT + r0 + lane] = s;
  }

  // ---- partial-output write: wave w owns cols [32w, 32w+32) ----
  float* pob = pout + (size_t)jb * NTOT * DDIM;
#pragma unroll
  for (int rt = 0; rt < 2; ++rt)
#pragma unroll
    for (int nn = 0; nn < 2; ++nn)
#pragma unroll
      for (int reg = 0; reg < 4; ++reg)
        pob[(size_t)(r0 + rt * 16 + quad * 4 + reg) * DDIM + w * 32 + nn * 16 + c] =
            acc[rt][nn][reg];
}

// ---------------- combine the 2 j-half partials, divide by denom ------------
__global__ __launch_bounds__(256) void gat_combine(const float* __restrict__ pout,
                                                   const float* __restrict__ plp,
                                                   float* __restrict__ out) {
  const int idx = blockIdx.x * 256 + threadIdx.x;   // float4-group index
  const int row = idx >> 6;                          // 64 float4 per row
  float4 a = ((const float4*)pout)[idx];
  float4 b = ((const float4*)(pout + (size_t)NTOT * DDIM))[idx];
  float inv = 1.f / (plp[row] + plp[NTOT + row]);
  float4 r;
  r.x = (a.x + b.x) * inv;
  r.y = (a.y + b.y) * inv;
  r.z = (a.z + b.z) * inv;
  r.w = (a.w + b.w) * inv;
  __builtin_nontemporal_store(r.x, &((float*)out)[idx * 4 + 0]);
  __builtin_nontemporal_store(r.y, &((float*)out)[idx * 4 + 1]);
  __builtin_nontemporal_store(r.z, &((float*)out)[idx * 4 + 2]);
  __builtin_nontemporal_store(r.w, &((float*)out)[idx * 4 + 3]);
}

extern "C" void kernel_launch(void* const* d_in, const int* in_sizes, int n_in,
                              void* d_out, int out_size, void* d_ws, size_t ws_size,
                              hipStream_t stream) {
  const float* h   = (const float*)d_in[0];
  const int*   adj = (const int*)d_in[1];
  const float* a   = (const float*)d_in[2];
  float* out = (float*)d_out;

  float4*   rc    = (float4*)d_ws;                       // 8192 float4 = 128 KB
  float2*   etab  = (float2*)(rc + NTOT);                // 8192 float2 = 64 KB
  ushort*   hTf   = (ushort*)(etab + NTOT);              // 4.21 MB bf16
  float*    pout  = (float*)(hTf + HTF_ELEMS);           // 2 x 8192 x 256 f32 = 16 MB
  float*    plp   = pout + (size_t)JSPL * NTOT * DDIM;   // 2 x 8192 f32

  gat_scores<<<NTOT / 4, 256, 0, stream>>>(h, a, rc, etab);
  gat_hpack<<<NTOT / 64, 256, 0, stream>>>(h, hTf);
  gat_attn<<<dim3(NTOT / ROWS, JSPL), 512, 0, stream>>>(hTf, adj, rc, etab, pout, plp);
  gat_combine<<<(NTOT * DDIM / 4) / 256, 256, 0, stream>>>(pout, plp, out);
}